// Round 8
// baseline (363.022 us; speedup 1.0000x reference)
//
#include <hip/hip_runtime.h>
#include <math.h>

#define N_NODES 50000
#define N_EDGES 800000
#define F_IN    512
#define H1      8
#define F_HID   8
#define C1      64      // H1*F_HID
#define NLAB    64
#define SLOPE   0.2f

#define NBLK_SCAN 196   // ceil(50000/256)
#define NBLK_HIST 782   // ceil(800000/4/256)
#define NBLK_WT   128   // 64*512/256
#define REC1     160    // [es1: 8 f32 | Wh1: 64 bf16] (always exactly 2 cache lines)
#define REC2     144    // [es2: f32, pad | Wh2: 64 bf16]

typedef __attribute__((ext_vector_type(8))) short short8;
typedef __attribute__((ext_vector_type(4))) float f32x4;

__device__ __forceinline__ float bf_lo(unsigned u) { return __uint_as_float(u << 16); }
__device__ __forceinline__ float bf_hi(unsigned u) { return __uint_as_float(u & 0xFFFF0000u); }
__device__ __forceinline__ unsigned short f2bf(float x) {
    unsigned bits = __float_as_uint(x);
    return (unsigned short)((bits + 0x7FFF + ((bits >> 16) & 1)) >> 16);   // RNE
}

// ---------------- fused: edge histogram (blocks 0..781) + W1 split (782..909) ----------
__global__ void k_histwt(const int* __restrict__ dst, int* __restrict__ deg,
                         const float* __restrict__ W1, unsigned short* __restrict__ Bh,
                         unsigned short* __restrict__ Bl) {
    int b = blockIdx.x;
    if (b < NBLK_HIST) {
        int e4 = (b * 256 + threadIdx.x) * 4;
        if (e4 >= N_EDGES) return;
        int4 d4 = *(const int4*)(dst + e4);
        atomicAdd(&deg[d4.x], 1);
        atomicAdd(&deg[d4.y], 1);
        atomicAdd(&deg[d4.z], 1);
        atomicAdd(&deg[d4.w], 1);
    } else {
        int i = (b - NBLK_HIST) * 256 + threadIdx.x;   // 0..32767
        int c = i >> 9, f = i & 511;
        float v = W1[(c >> 3) * (F_IN * F_HID) + f * F_HID + (c & 7)];
        unsigned bits = __float_as_uint(v);
        float r = v - __uint_as_float(bits & 0xFFFF0000u);
        Bh[i] = (unsigned short)(bits >> 16);
        Bl[i] = (unsigned short)(__float_as_uint(r) >> 16);
    }
}

__global__ void k_scan1(const int* __restrict__ deg, int* __restrict__ rowptr,
                        int* __restrict__ bsums) {
    __shared__ int s[256];
    int t = threadIdx.x;
    int g = blockIdx.x * 256 + t;
    int v = (g < N_NODES) ? deg[g] : 0;
    s[t] = v;
    __syncthreads();
    #pragma unroll
    for (int off = 1; off < 256; off <<= 1) {
        int a = s[t];
        int b = (t >= off) ? s[t - off] : 0;
        __syncthreads();
        s[t] = a + b;
        __syncthreads();
    }
    if (g < N_NODES) rowptr[g] = s[t] - v;
    if (t == 255) bsums[blockIdx.x] = s[t];
}

__global__ void k_scan23(const int* __restrict__ bsums, int* __restrict__ rowptr) {
    __shared__ int s[256];
    int t = threadIdx.x;
    s[t] = (t < NBLK_SCAN) ? bsums[t] : 0;
    __syncthreads();
    #pragma unroll
    for (int off = 1; off < 256; off <<= 1) {
        int a = s[t];
        int b = (t >= off) ? s[t - off] : 0;
        __syncthreads();
        s[t] = a + b;
        __syncthreads();
    }
    int boff = (blockIdx.x == 0) ? 0 : s[blockIdx.x - 1];
    int g = blockIdx.x * 256 + t;
    if (g < N_NODES) rowptr[g] += boff;
}

// scatter: post-increments rowptr (ends at start+deg; consumers subtract deg)
__global__ void k_scatter(const int* __restrict__ src, const int* __restrict__ dst,
                          int* __restrict__ rowptr, int* __restrict__ col) {
    int e4 = (blockIdx.x * 256 + threadIdx.x) * 4;
    if (e4 >= N_EDGES) return;
    int4 s4 = *(const int4*)(src + e4);
    int4 d4 = *(const int4*)(dst + e4);
    col[atomicAdd(&rowptr[d4.x], 1)] = s4.x;
    col[atomicAdd(&rowptr[d4.y], 1)] = s4.y;
    col[atomicAdd(&rowptr[d4.z], 1)] = s4.z;
    col[atomicAdd(&rowptr[d4.w], 1)] = s4.w;
}

// ---------------- GEMM1 + fused es/ed/record pack ----------------
// 256 thr / 4 waves / 64 rows. B hi/lo in LDS per K-chunk of 128, depth-4 X prefetch.
// Epilogue: acc -> LDS (bf16) -> per-lane es/ed dots -> rec1 + ed1. No Wh global trip.
__launch_bounds__(256)
__global__ void k_gemm1p(const float* __restrict__ X, const unsigned short* __restrict__ Bh,
                         const unsigned short* __restrict__ Bl, const float* __restrict__ a_s,
                         const float* __restrict__ a_d, char* __restrict__ rec,
                         float* __restrict__ ed) {
    __shared__ unsigned short sBh[64][136];
    __shared__ unsigned short sBl[64][136];
    const int t = threadIdx.x;
    const int lane = t & 63, w = t >> 6;
    const int r0 = blockIdx.x * 64 + w * 16;
    const int m = lane & 15, quad = lane >> 4;
    int row = r0 + m; if (row >= N_NODES) row = N_NODES - 1;
    const float* xrow = X + (size_t)row * F_IN + quad * 8;

    const int sc = t >> 2;        // staging col 0..63
    const int sp = t & 3;         // staging quarter 0..3

    f32x4 acc[4] = {};
    float4 pxa[4], pxb[4];
    #pragma unroll
    for (int i = 0; i < 4; i++) {
        pxa[i] = *(const float4*)(xrow + i * 32);
        pxb[i] = *(const float4*)(xrow + i * 32 + 4);
    }

    for (int chunk = 0; chunk < 4; chunk++) {
        const int k0 = chunk * 128;
        if (chunk) __syncthreads();
        #pragma unroll
        for (int i = 0; i < 4; i++) {
            *(short8*)(&sBh[sc][sp * 32 + i * 8]) =
                *(const short8*)(Bh + sc * F_IN + k0 + sp * 32 + i * 8);
            *(short8*)(&sBl[sc][sp * 32 + i * 8]) =
                *(const short8*)(Bl + sc * F_IN + k0 + sp * 32 + i * 8);
        }
        __syncthreads();
        #pragma unroll
        for (int i = 0; i < 4; i++) {
            float xs[8] = {pxa[i].x, pxa[i].y, pxa[i].z, pxa[i].w,
                           pxb[i].x, pxb[i].y, pxb[i].z, pxb[i].w};
            if (chunk < 3) {
                const int ktn = k0 + 128 + i * 32;
                pxa[i] = *(const float4*)(xrow + ktn);
                pxb[i] = *(const float4*)(xrow + ktn + 4);
            }
            short8 ah, al;
            #pragma unroll
            for (int j = 0; j < 8; j++) {
                unsigned bits = __float_as_uint(xs[j]);
                float r = xs[j] - __uint_as_float(bits & 0xFFFF0000u);
                ah[j] = (short)(bits >> 16);
                al[j] = (short)(__float_as_uint(r) >> 16);
            }
            #pragma unroll
            for (int s = 0; s < 4; s++) {
                short8 bh = *(const short8*)(&sBh[s * 16 + m][i * 32 + quad * 8]);
                short8 bl = *(const short8*)(&sBl[s * 16 + m][i * 32 + quad * 8]);
                acc[s] = __builtin_amdgcn_mfma_f32_16x16x32_bf16(al, bh, acc[s], 0, 0, 0);
                acc[s] = __builtin_amdgcn_mfma_f32_16x16x32_bf16(ah, bl, acc[s], 0, 0, 0);
                acc[s] = __builtin_amdgcn_mfma_f32_16x16x32_bf16(ah, bh, acc[s], 0, 0, 0);
            }
        }
    }
    // ---- fused pack epilogue ----
    __syncthreads();                        // all MFMA LDS reads done; safe to reuse
    unsigned short* sWh = &sBh[0][0] + w * 1024;   // 16 rows x 64 cols bf16, per wave
    #pragma unroll
    for (int s = 0; s < 4; s++)
        #pragma unroll
        for (int reg = 0; reg < 4; reg++)
            sWh[(quad * 4 + reg) * 64 + s * 16 + m] = f2bf(acc[s][reg]);
    __syncthreads();
    // lane -> (row rr = lane&15, part p = lane>>4); lane handles heads 2p, 2p+1
    // and writes its 16 channels (p*16 .. p*16+15) of the record = 32 bytes.
    const int rr = lane & 15, p = lane >> 4;
    const int n = r0 + rr;
    if (n >= N_NODES) return;               // wave-uniform enough (tail block only)
    float es2v[2], edv[2];
    #pragma unroll
    for (int hh = 0; hh < 2; hh++) {
        int h = 2 * p + hh;
        float s = 0.f, dsum = 0.f;
        #pragma unroll
        for (int j = 0; j < 8; j++) {
            float v = __uint_as_float((unsigned)sWh[rr * 64 + h * 8 + j] << 16);
            s += v * a_s[h * 8 + j];
            dsum += v * a_d[h * 8 + j];
        }
        es2v[hh] = s; edv[hh] = dsum;
    }
    char* r = rec + (size_t)n * REC1;
    *(float2*)(r + p * 8) = make_float2(es2v[0], es2v[1]);
    *(short8*)(r + 32 + p * 32)      = *(const short8*)(sWh + rr * 64 + p * 16);      // ch p*16..+7
    *(short8*)(r + 32 + p * 32 + 16) = *(const short8*)(sWh + rr * 64 + p * 16 + 8);  // ch p*16+8..+15
    *(float2*)(ed + n * 8 + 2 * p) = make_float2(edv[0], edv[1]);
}

// ---------------- fused layer-1 aggregation + GEMM2 + es2/ed2 ----------------
// wave per node. Gather phase as before; then the full h2 row lives replicated
// across the 8 q-lanes -> in-wave 64x64 matmul via shfl broadcast + W2 from L2.
__launch_bounds__(256)
__global__ void k_agg1g2(const char* __restrict__ rec, const float* __restrict__ ed,
                         const int* __restrict__ rowptr, const int* __restrict__ deg,
                         const int* __restrict__ col, const float* __restrict__ W2,
                         const float* __restrict__ a2s, const float* __restrict__ a2d,
                         char* __restrict__ rec2, float* __restrict__ ed2) {
    int wv = threadIdx.x >> 6, lane = threadIdx.x & 63;
    int n = blockIdx.x * 4 + wv;
    if (n >= N_NODES) return;
    int d = deg[n];
    int start = rowptr[n] - d;
    int g = lane >> 3, q = lane & 7;
    float edq = ed[n * 8 + q];

    float den = 0.f;
    float acc[8] = {};
    for (int base = 0; base < d; base += 16) {
        int e0 = base + g, e1 = base + 8 + g;
        int sv0 = col[start + min(e0, d - 1)];
        int sv1 = col[start + min(e1, d - 1)];
        const char* r0 = rec + (size_t)sv0 * REC1;
        const char* r1 = rec + (size_t)sv1 * REC1;
        float x0 = *(const float*)(r0 + q * 4) + edq;
        float x1 = *(const float*)(r1 + q * 4) + edq;
        uint4 u0 = *(const uint4*)(r0 + 32 + q * 16);
        uint4 u1 = *(const uint4*)(r1 + 32 + q * 16);
        x0 = x0 > 0.f ? x0 : SLOPE * x0;
        x1 = x1 > 0.f ? x1 : SLOPE * x1;
        float w0 = (e0 < d) ? __expf(x0) : 0.f;
        float w1 = (e1 < d) ? __expf(x1) : 0.f;
        den += w0 + w1;
        float f0[8] = {bf_lo(u0.x), bf_hi(u0.x), bf_lo(u0.y), bf_hi(u0.y),
                       bf_lo(u0.z), bf_hi(u0.z), bf_lo(u0.w), bf_hi(u0.w)};
        float f1[8] = {bf_lo(u1.x), bf_hi(u1.x), bf_lo(u1.y), bf_hi(u1.y),
                       bf_lo(u1.z), bf_hi(u1.z), bf_lo(u1.w), bf_hi(u1.w)};
        #pragma unroll
        for (int j = 0; j < 8; j++) acc[j] += w0 * f0[j] + w1 * f1[j];
    }
    #pragma unroll
    for (int off = 8; off <= 32; off <<= 1) {
        den += __shfl_xor(den, off);
        #pragma unroll
        for (int j = 0; j < 8; j++) acc[j] += __shfl_xor(acc[j], off);
    }
    // all lanes now hold the reduced row; lane (g,q) has channels q*8+j
    float inv = 1.f / (den + 1e-10f);
    float o[8];
    #pragma unroll
    for (int j = 0; j < 8; j++) {
        float v = acc[j] * inv;
        o[j] = v > 0.f ? v : expm1f(v);      // fused ELU -> h2 value
    }
    // in-wave GEMM2: out[c=lane] = sum_k h[k] * W2[k*64+c], h[k] = shfl(o[k&7], k>>3)
    float out_c = 0.f;
    #pragma unroll
    for (int j = 0; j < 8; j++)
        #pragma unroll
        for (int qq = 0; qq < 8; qq++) {
            float hk = __shfl(o[j], qq);     // lane qq has g=0,q=qq
            out_c += hk * W2[(qq * 8 + j) * 64 + lane];
        }
    // record2 + es2/ed2
    char* r2 = rec2 + (size_t)n * REC2;
    *(unsigned short*)(r2 + 16 + lane * 2) = f2bf(out_c);
    float s = out_c * a2s[lane];
    float dd = out_c * a2d[lane];
    #pragma unroll
    for (int off = 1; off < 64; off <<= 1) {
        s += __shfl_xor(s, off);
        dd += __shfl_xor(dd, off);
    }
    if (lane == 0) { *(float*)r2 = s; ed2[n] = dd; }
}

// ---------------- layer-2 aggregation + fused final softmax ----------------
__launch_bounds__(256)
__global__ void k_agg2(const char* __restrict__ rec2, const float* __restrict__ ed2,
                       const int* __restrict__ rowptr, const int* __restrict__ deg,
                       const int* __restrict__ col, float* __restrict__ out) {
    int wv = threadIdx.x >> 6, lane = threadIdx.x & 63;
    int n = blockIdx.x * 4 + wv;
    if (n >= N_NODES) return;
    int d = deg[n];
    int start = rowptr[n] - d;
    int g = lane >> 3, q = lane & 7;
    float edn = ed2[n];

    float den = 0.f;
    float acc[8] = {};
    for (int base = 0; base < d; base += 16) {
        int e0 = base + g, e1 = base + 8 + g;
        int sv0 = col[start + min(e0, d - 1)];
        int sv1 = col[start + min(e1, d - 1)];
        const char* r0 = rec2 + (size_t)sv0 * REC2;
        const char* r1 = rec2 + (size_t)sv1 * REC2;
        float x0 = *(const float*)r0 + edn;
        float x1 = *(const float*)r1 + edn;
        uint4 u0 = *(const uint4*)(r0 + 16 + q * 16);
        uint4 u1 = *(const uint4*)(r1 + 16 + q * 16);
        x0 = x0 > 0.f ? x0 : SLOPE * x0;
        x1 = x1 > 0.f ? x1 : SLOPE * x1;
        float w0 = (e0 < d) ? __expf(x0) : 0.f;
        float w1 = (e1 < d) ? __expf(x1) : 0.f;
        den += w0 + w1;
        float f0[8] = {bf_lo(u0.x), bf_hi(u0.x), bf_lo(u0.y), bf_hi(u0.y),
                       bf_lo(u0.z), bf_hi(u0.z), bf_lo(u0.w), bf_hi(u0.w)};
        float f1[8] = {bf_lo(u1.x), bf_hi(u1.x), bf_lo(u1.y), bf_hi(u1.y),
                       bf_lo(u1.z), bf_hi(u1.z), bf_lo(u1.w), bf_hi(u1.w)};
        #pragma unroll
        for (int j = 0; j < 8; j++) acc[j] += w0 * f0[j] + w1 * f1[j];
    }
    #pragma unroll
    for (int off = 8; off <= 32; off <<= 1) {
        den += __shfl_xor(den, off);
        #pragma unroll
        for (int j = 0; j < 8; j++) acc[j] += __shfl_xor(acc[j], off);
    }
    float inv = 1.f / (den + 1e-10f);
    float o[8];
    #pragma unroll
    for (int j = 0; j < 8; j++) o[j] = acc[j] * inv;
    float mx = o[0];
    #pragma unroll
    for (int j = 1; j < 8; j++) mx = fmaxf(mx, o[j]);
    mx = fmaxf(mx, __shfl_xor(mx, 1));
    mx = fmaxf(mx, __shfl_xor(mx, 2));
    mx = fmaxf(mx, __shfl_xor(mx, 4));
    float e8[8], sm = 0.f;
    #pragma unroll
    for (int j = 0; j < 8; j++) { e8[j] = __expf(o[j] - mx); sm += e8[j]; }
    sm += __shfl_xor(sm, 1);
    sm += __shfl_xor(sm, 2);
    sm += __shfl_xor(sm, 4);
    if (g == 0) {
        float inv2 = 1.f / sm;
        float4* op = (float4*)(out + (size_t)n * 64 + q * 8);
        op[0] = make_float4(e8[0] * inv2, e8[1] * inv2, e8[2] * inv2, e8[3] * inv2);
        op[1] = make_float4(e8[4] * inv2, e8[5] * inv2, e8[6] * inv2, e8[7] * inv2);
    }
}

// ---------------- launcher (8 dispatches) ----------------
extern "C" void kernel_launch(void* const* d_in, const int* in_sizes, int n_in,
                              void* d_out, int out_size, void* d_ws, size_t ws_size,
                              hipStream_t stream) {
    const float* X   = (const float*)d_in[0];
    const float* W1  = (const float*)d_in[1];
    const float* a1s = (const float*)d_in[2];
    const float* a1d = (const float*)d_in[3];
    const float* W2  = (const float*)d_in[4];
    const float* a2s = (const float*)d_in[5];
    const float* a2d = (const float*)d_in[6];
    const int*   src = (const int*)d_in[7];
    const int*   dst = (const int*)d_in[8];
    float* out = (float*)d_out;

    char* w = (char*)d_ws;
    size_t off = 0;
    auto alloc = [&](size_t bytes) {
        void* p = w + off;
        off += (bytes + 255) & ~(size_t)255;
        return p;
    };
    unsigned short* Bh  = (unsigned short*)alloc((size_t)C1 * F_IN * 2);
    unsigned short* Bl  = (unsigned short*)alloc((size_t)C1 * F_IN * 2);
    char*  rec1  = (char*)alloc((size_t)N_NODES * REC1);
    char*  rec2  = (char*)alloc((size_t)N_NODES * REC2);
    float* ed1   = (float*)alloc((size_t)N_NODES * 8 * 4);
    float* ed2   = (float*)alloc((size_t)N_NODES * 4);
    int*   deg   = (int*)alloc((size_t)N_NODES * 4);
    int*   rowptr= (int*)alloc((size_t)N_NODES * 4);
    int*   col   = (int*)alloc((size_t)N_EDGES * 4);
    int*   bsums = (int*)alloc(256 * 4);

    hipMemsetAsync(deg, 0, (size_t)N_NODES * 4, stream);

    k_histwt<<<NBLK_HIST + NBLK_WT, 256, 0, stream>>>(dst, deg, W1, Bh, Bl);
    k_scan1<<<NBLK_SCAN, 256, 0, stream>>>(deg, rowptr, bsums);
    k_scan23<<<NBLK_SCAN, 256, 0, stream>>>(bsums, rowptr);
    k_scatter<<<(N_EDGES / 4 + 255) / 256, 256, 0, stream>>>(src, dst, rowptr, col);

    k_gemm1p<<<(N_NODES + 63) / 64, 256, 0, stream>>>(X, Bh, Bl, a1s, a1d, rec1, ed1);
    k_agg1g2<<<(N_NODES + 3) / 4, 256, 0, stream>>>(rec1, ed1, rowptr, deg, col,
                                                    W2, a2s, a2d, rec2, ed2);
    k_agg2<<<(N_NODES + 3) / 4, 256, 0, stream>>>(rec2, ed2, rowptr, deg, col, out);
}

// Round 9
// 347.256 us; speedup vs baseline: 1.0454x; 1.0454x over previous
//
#include <hip/hip_runtime.h>
#include <math.h>

#define N_NODES 50000
#define N_EDGES 800000
#define F_IN    512
#define H1      8
#define F_HID   8
#define C1      64      // H1*F_HID
#define NLAB    64
#define SLOPE   0.2f

#define NBLK_SCAN 196   // ceil(50000/256)
#define NBLK_HIST 782   // ceil(800000/4/256)
#define NBLK_WT   128   // 64*512/256
#define REC1     160    // [es1: 8 f32 | Wh1: 64 bf16] (2 cache lines)
#define REC2     144    // [es2: f32, pad | Wh2: 64 bf16]

typedef __attribute__((ext_vector_type(8))) short short8;
typedef __attribute__((ext_vector_type(4))) float f32x4;

__device__ __forceinline__ float bf_lo(unsigned u) { return __uint_as_float(u << 16); }
__device__ __forceinline__ float bf_hi(unsigned u) { return __uint_as_float(u & 0xFFFF0000u); }
__device__ __forceinline__ unsigned short f2bf(float x) {
    unsigned bits = __float_as_uint(x);
    return (unsigned short)((bits + 0x7FFF + ((bits >> 16) & 1)) >> 16);   // RNE
}

// ---------------- fused: edge histogram (blocks 0..781) + W1 split (782..909) ----------
__global__ void k_histwt(const int* __restrict__ dst, int* __restrict__ deg,
                         const float* __restrict__ W1, unsigned short* __restrict__ Bh,
                         unsigned short* __restrict__ Bl) {
    int b = blockIdx.x;
    if (b < NBLK_HIST) {
        int e4 = (b * 256 + threadIdx.x) * 4;
        if (e4 >= N_EDGES) return;
        int4 d4 = *(const int4*)(dst + e4);
        atomicAdd(&deg[d4.x], 1);
        atomicAdd(&deg[d4.y], 1);
        atomicAdd(&deg[d4.z], 1);
        atomicAdd(&deg[d4.w], 1);
    } else {
        int i = (b - NBLK_HIST) * 256 + threadIdx.x;   // 0..32767
        int c = i >> 9, f = i & 511;
        float v = W1[(c >> 3) * (F_IN * F_HID) + f * F_HID + (c & 7)];
        unsigned bits = __float_as_uint(v);
        float r = v - __uint_as_float(bits & 0xFFFF0000u);
        Bh[i] = (unsigned short)(bits >> 16);
        Bl[i] = (unsigned short)(__float_as_uint(r) >> 16);
    }
}

__global__ void k_scan1(const int* __restrict__ deg, int* __restrict__ rowptr,
                        int* __restrict__ bsums) {
    __shared__ int s[256];
    int t = threadIdx.x;
    int g = blockIdx.x * 256 + t;
    int v = (g < N_NODES) ? deg[g] : 0;
    s[t] = v;
    __syncthreads();
    #pragma unroll
    for (int off = 1; off < 256; off <<= 1) {
        int a = s[t];
        int b = (t >= off) ? s[t - off] : 0;
        __syncthreads();
        s[t] = a + b;
        __syncthreads();
    }
    if (g < N_NODES) rowptr[g] = s[t] - v;
    if (t == 255) bsums[blockIdx.x] = s[t];
}

__global__ void k_scan23(const int* __restrict__ bsums, int* __restrict__ rowptr) {
    __shared__ int s[256];
    int t = threadIdx.x;
    s[t] = (t < NBLK_SCAN) ? bsums[t] : 0;
    __syncthreads();
    #pragma unroll
    for (int off = 1; off < 256; off <<= 1) {
        int a = s[t];
        int b = (t >= off) ? s[t - off] : 0;
        __syncthreads();
        s[t] = a + b;
        __syncthreads();
    }
    int boff = (blockIdx.x == 0) ? 0 : s[blockIdx.x - 1];
    int g = blockIdx.x * 256 + t;
    if (g < N_NODES) rowptr[g] += boff;
}

// scatter: post-increments rowptr (ends at start+deg; consumers subtract deg)
__global__ void k_scatter(const int* __restrict__ src, const int* __restrict__ dst,
                          int* __restrict__ rowptr, int* __restrict__ col) {
    int e4 = (blockIdx.x * 256 + threadIdx.x) * 4;
    if (e4 >= N_EDGES) return;
    int4 s4 = *(const int4*)(src + e4);
    int4 d4 = *(const int4*)(dst + e4);
    col[atomicAdd(&rowptr[d4.x], 1)] = s4.x;
    col[atomicAdd(&rowptr[d4.y], 1)] = s4.y;
    col[atomicAdd(&rowptr[d4.z], 1)] = s4.z;
    col[atomicAdd(&rowptr[d4.w], 1)] = s4.w;
}

// ---------------- GEMM1 + fused es/ed/record pack (unchanged from R8, passed) ----------
__launch_bounds__(256)
__global__ void k_gemm1p(const float* __restrict__ X, const unsigned short* __restrict__ Bh,
                         const unsigned short* __restrict__ Bl, const float* __restrict__ a_s,
                         const float* __restrict__ a_d, char* __restrict__ rec,
                         float* __restrict__ ed) {
    __shared__ unsigned short sBh[64][136];
    __shared__ unsigned short sBl[64][136];
    const int t = threadIdx.x;
    const int lane = t & 63, w = t >> 6;
    const int r0 = blockIdx.x * 64 + w * 16;
    const int m = lane & 15, quad = lane >> 4;
    int row = r0 + m; if (row >= N_NODES) row = N_NODES - 1;
    const float* xrow = X + (size_t)row * F_IN + quad * 8;

    const int sc = t >> 2;
    const int sp = t & 3;

    f32x4 acc[4] = {};
    float4 pxa[4], pxb[4];
    #pragma unroll
    for (int i = 0; i < 4; i++) {
        pxa[i] = *(const float4*)(xrow + i * 32);
        pxb[i] = *(const float4*)(xrow + i * 32 + 4);
    }

    for (int chunk = 0; chunk < 4; chunk++) {
        const int k0 = chunk * 128;
        if (chunk) __syncthreads();
        #pragma unroll
        for (int i = 0; i < 4; i++) {
            *(short8*)(&sBh[sc][sp * 32 + i * 8]) =
                *(const short8*)(Bh + sc * F_IN + k0 + sp * 32 + i * 8);
            *(short8*)(&sBl[sc][sp * 32 + i * 8]) =
                *(const short8*)(Bl + sc * F_IN + k0 + sp * 32 + i * 8);
        }
        __syncthreads();
        #pragma unroll
        for (int i = 0; i < 4; i++) {
            float xs[8] = {pxa[i].x, pxa[i].y, pxa[i].z, pxa[i].w,
                           pxb[i].x, pxb[i].y, pxb[i].z, pxb[i].w};
            if (chunk < 3) {
                const int ktn = k0 + 128 + i * 32;
                pxa[i] = *(const float4*)(xrow + ktn);
                pxb[i] = *(const float4*)(xrow + ktn + 4);
            }
            short8 ah, al;
            #pragma unroll
            for (int j = 0; j < 8; j++) {
                unsigned bits = __float_as_uint(xs[j]);
                float r = xs[j] - __uint_as_float(bits & 0xFFFF0000u);
                ah[j] = (short)(bits >> 16);
                al[j] = (short)(__float_as_uint(r) >> 16);
            }
            #pragma unroll
            for (int s = 0; s < 4; s++) {
                short8 bh = *(const short8*)(&sBh[s * 16 + m][i * 32 + quad * 8]);
                short8 bl = *(const short8*)(&sBl[s * 16 + m][i * 32 + quad * 8]);
                acc[s] = __builtin_amdgcn_mfma_f32_16x16x32_bf16(al, bh, acc[s], 0, 0, 0);
                acc[s] = __builtin_amdgcn_mfma_f32_16x16x32_bf16(ah, bl, acc[s], 0, 0, 0);
                acc[s] = __builtin_amdgcn_mfma_f32_16x16x32_bf16(ah, bh, acc[s], 0, 0, 0);
            }
        }
    }
    __syncthreads();
    unsigned short* sWh = &sBh[0][0] + w * 1024;
    #pragma unroll
    for (int s = 0; s < 4; s++)
        #pragma unroll
        for (int reg = 0; reg < 4; reg++)
            sWh[(quad * 4 + reg) * 64 + s * 16 + m] = f2bf(acc[s][reg]);
    __syncthreads();
    const int rr = lane & 15, p = lane >> 4;
    const int n = r0 + rr;
    if (n >= N_NODES) return;
    float es2v[2], edv[2];
    #pragma unroll
    for (int hh = 0; hh < 2; hh++) {
        int h = 2 * p + hh;
        float s = 0.f, dsum = 0.f;
        #pragma unroll
        for (int j = 0; j < 8; j++) {
            float v = __uint_as_float((unsigned)sWh[rr * 64 + h * 8 + j] << 16);
            s += v * a_s[h * 8 + j];
            dsum += v * a_d[h * 8 + j];
        }
        es2v[hh] = s; edv[hh] = dsum;
    }
    char* r = rec + (size_t)n * REC1;
    *(float2*)(r + p * 8) = make_float2(es2v[0], es2v[1]);
    *(short8*)(r + 32 + p * 32)      = *(const short8*)(sWh + rr * 64 + p * 16);
    *(short8*)(r + 32 + p * 32 + 16) = *(const short8*)(sWh + rr * 64 + p * 16 + 8);
    *(float2*)(ed + n * 8 + 2 * p) = make_float2(edv[0], edv[1]);
}

// ---------------- layer-1 aggregation: GROUP-PER-NODE (8 lanes/node) ----------------
// lane q of each 8-lane group owns head q (= channels 8q..8q+7). No cross-group
// reduction: den and acc are lane-private. 2x edge unroll for ILP.
__launch_bounds__(256)
__global__ void k_agg1(const char* __restrict__ rec, const float* __restrict__ ed,
                       const int* __restrict__ rowptr, const int* __restrict__ deg,
                       const int* __restrict__ col, float* __restrict__ h2) {
    int tid = blockIdx.x * 256 + threadIdx.x;
    int n = tid >> 3, q = tid & 7;
    if (n >= N_NODES) return;
    int d = deg[n];
    int start = rowptr[n] - d;
    float edq = ed[n * 8 + q];

    float den = 0.f;
    float acc[8] = {};
    for (int e = 0; e < d; e += 2) {
        int sv0 = col[start + e];
        int sv1 = col[start + min(e + 1, d - 1)];
        const char* r0 = rec + (size_t)sv0 * REC1;
        const char* r1 = rec + (size_t)sv1 * REC1;
        float x0 = *(const float*)(r0 + q * 4) + edq;
        float x1 = *(const float*)(r1 + q * 4) + edq;
        uint4 u0 = *(const uint4*)(r0 + 32 + q * 16);
        uint4 u1 = *(const uint4*)(r1 + 32 + q * 16);
        x0 = x0 > 0.f ? x0 : SLOPE * x0;
        x1 = x1 > 0.f ? x1 : SLOPE * x1;
        float w0 = __expf(x0);
        float w1 = (e + 1 < d) ? __expf(x1) : 0.f;
        den += w0 + w1;
        float f0[8] = {bf_lo(u0.x), bf_hi(u0.x), bf_lo(u0.y), bf_hi(u0.y),
                       bf_lo(u0.z), bf_hi(u0.z), bf_lo(u0.w), bf_hi(u0.w)};
        float f1[8] = {bf_lo(u1.x), bf_hi(u1.x), bf_lo(u1.y), bf_hi(u1.y),
                       bf_lo(u1.z), bf_hi(u1.z), bf_lo(u1.w), bf_hi(u1.w)};
        #pragma unroll
        for (int j = 0; j < 8; j++) acc[j] += w0 * f0[j] + w1 * f1[j];
    }
    float inv = 1.f / (den + 1e-10f);
    float o[8];
    #pragma unroll
    for (int j = 0; j < 8; j++) {
        float v = acc[j] * inv;
        o[j] = v > 0.f ? v : expm1f(v);   // fused ELU
    }
    float4* hp = (float4*)(h2 + (size_t)n * 64 + q * 8);
    hp[0] = make_float4(o[0], o[1], o[2], o[3]);
    hp[1] = make_float4(o[4], o[5], o[6], o[7]);
}

// ---------------- GEMM2 (K=64), 16 nodes/block; writes record2 + ed2 ----------------
__launch_bounds__(256)
__global__ void k_gemm2(const float* __restrict__ h2, const float* __restrict__ W2,
                        const float* __restrict__ a2s, const float* __restrict__ a2d,
                        char* __restrict__ rec2, float* __restrict__ ed2) {
    __shared__ float Ws[64 * 64];
    __shared__ float hs[16][64];
    int t = threadIdx.x;
    int n0 = blockIdx.x * 16;
    #pragma unroll
    for (int i = 0; i < 4; i++) {
        int flat = i * 256 + t;
        *(float4*)(Ws + flat * 4) = *(const float4*)(W2 + flat * 4);
    }
    #pragma unroll
    for (int i = 0; i < 4; i++) {
        int flat = i * 256 + t;
        hs[flat >> 6][flat & 63] = h2[(size_t)(n0 + (flat >> 6)) * 64 + (flat & 63)];
    }
    __syncthreads();
    int wv = t >> 6, lane = t & 63;
    float as = a2s[lane], ad = a2d[lane];
    #pragma unroll
    for (int j = 0; j < 4; j++) {
        int nl = wv * 4 + j;
        int n = n0 + nl;
        float acc = 0.f;
        #pragma unroll
        for (int k = 0; k < 64; k++) acc += hs[nl][k] * Ws[k * 64 + lane];
        char* r = rec2 + (size_t)n * REC2;
        *(unsigned short*)(r + 16 + lane * 2) = f2bf(acc);
        float s = acc * as;
        float dd = acc * ad;
        #pragma unroll
        for (int off = 1; off < 64; off <<= 1) {
            s += __shfl_xor(s, off);
            dd += __shfl_xor(dd, off);
        }
        if (lane == 0) { *(float*)r = s; ed2[n] = dd; }
    }
}

// ---------------- layer-2 aggregation: GROUP-PER-NODE + fused final softmax ----------
__launch_bounds__(256)
__global__ void k_agg2(const char* __restrict__ rec2, const float* __restrict__ ed2,
                       const int* __restrict__ rowptr, const int* __restrict__ deg,
                       const int* __restrict__ col, float* __restrict__ out) {
    int tid = blockIdx.x * 256 + threadIdx.x;
    int n = tid >> 3, q = tid & 7;
    if (n >= N_NODES) return;
    int d = deg[n];
    int start = rowptr[n] - d;
    float edn = ed2[n];

    float den = 0.f;
    float acc[8] = {};
    for (int e = 0; e < d; e += 2) {
        int sv0 = col[start + e];
        int sv1 = col[start + min(e + 1, d - 1)];
        const char* r0 = rec2 + (size_t)sv0 * REC2;
        const char* r1 = rec2 + (size_t)sv1 * REC2;
        float x0 = *(const float*)r0 + edn;
        float x1 = *(const float*)r1 + edn;
        uint4 u0 = *(const uint4*)(r0 + 16 + q * 16);
        uint4 u1 = *(const uint4*)(r1 + 16 + q * 16);
        x0 = x0 > 0.f ? x0 : SLOPE * x0;
        x1 = x1 > 0.f ? x1 : SLOPE * x1;
        float w0 = __expf(x0);
        float w1 = (e + 1 < d) ? __expf(x1) : 0.f;
        den += w0 + w1;
        float f0[8] = {bf_lo(u0.x), bf_hi(u0.x), bf_lo(u0.y), bf_hi(u0.y),
                       bf_lo(u0.z), bf_hi(u0.z), bf_lo(u0.w), bf_hi(u0.w)};
        float f1[8] = {bf_lo(u1.x), bf_hi(u1.x), bf_lo(u1.y), bf_hi(u1.y),
                       bf_lo(u1.z), bf_hi(u1.z), bf_lo(u1.w), bf_hi(u1.w)};
        #pragma unroll
        for (int j = 0; j < 8; j++) acc[j] += w0 * f0[j] + w1 * f1[j];
    }
    float inv = 1.f / (den + 1e-10f);
    float o[8];
    #pragma unroll
    for (int j = 0; j < 8; j++) o[j] = acc[j] * inv;
    // softmax over 64 classes spread across the 8-lane group (xor 1,2,4 stays in-group)
    float mx = o[0];
    #pragma unroll
    for (int j = 1; j < 8; j++) mx = fmaxf(mx, o[j]);
    mx = fmaxf(mx, __shfl_xor(mx, 1));
    mx = fmaxf(mx, __shfl_xor(mx, 2));
    mx = fmaxf(mx, __shfl_xor(mx, 4));
    float e8[8], sm = 0.f;
    #pragma unroll
    for (int j = 0; j < 8; j++) { e8[j] = __expf(o[j] - mx); sm += e8[j]; }
    sm += __shfl_xor(sm, 1);
    sm += __shfl_xor(sm, 2);
    sm += __shfl_xor(sm, 4);
    float inv2 = 1.f / sm;
    float4* op = (float4*)(out + (size_t)n * 64 + q * 8);
    op[0] = make_float4(e8[0] * inv2, e8[1] * inv2, e8[2] * inv2, e8[3] * inv2);
    op[1] = make_float4(e8[4] * inv2, e8[5] * inv2, e8[6] * inv2, e8[7] * inv2);
}

// ---------------- launcher (9 dispatches) ----------------
extern "C" void kernel_launch(void* const* d_in, const int* in_sizes, int n_in,
                              void* d_out, int out_size, void* d_ws, size_t ws_size,
                              hipStream_t stream) {
    const float* X   = (const float*)d_in[0];
    const float* W1  = (const float*)d_in[1];
    const float* a1s = (const float*)d_in[2];
    const float* a1d = (const float*)d_in[3];
    const float* W2  = (const float*)d_in[4];
    const float* a2s = (const float*)d_in[5];
    const float* a2d = (const float*)d_in[6];
    const int*   src = (const int*)d_in[7];
    const int*   dst = (const int*)d_in[8];
    float* out = (float*)d_out;

    char* w = (char*)d_ws;
    size_t off = 0;
    auto alloc = [&](size_t bytes) {
        void* p = w + off;
        off += (bytes + 255) & ~(size_t)255;
        return p;
    };
    unsigned short* Bh  = (unsigned short*)alloc((size_t)C1 * F_IN * 2);
    unsigned short* Bl  = (unsigned short*)alloc((size_t)C1 * F_IN * 2);
    char*  rec1  = (char*)alloc((size_t)N_NODES * REC1);
    char*  rec2  = (char*)alloc((size_t)N_NODES * REC2);
    float* h2    = (float*)alloc((size_t)N_NODES * 64 * 4);
    float* ed1   = (float*)alloc((size_t)N_NODES * 8 * 4);
    float* ed2   = (float*)alloc((size_t)N_NODES * 4);
    int*   deg   = (int*)alloc((size_t)N_NODES * 4);
    int*   rowptr= (int*)alloc((size_t)N_NODES * 4);
    int*   col   = (int*)alloc((size_t)N_EDGES * 4);
    int*   bsums = (int*)alloc(256 * 4);

    hipMemsetAsync(deg, 0, (size_t)N_NODES * 4, stream);

    k_histwt<<<NBLK_HIST + NBLK_WT, 256, 0, stream>>>(dst, deg, W1, Bh, Bl);
    k_scan1<<<NBLK_SCAN, 256, 0, stream>>>(deg, rowptr, bsums);
    k_scan23<<<NBLK_SCAN, 256, 0, stream>>>(bsums, rowptr);
    k_scatter<<<(N_EDGES / 4 + 255) / 256, 256, 0, stream>>>(src, dst, rowptr, col);

    k_gemm1p<<<(N_NODES + 63) / 64, 256, 0, stream>>>(X, Bh, Bl, a1s, a1d, rec1, ed1);
    k_agg1<<<(N_NODES * 8 + 255) / 256, 256, 0, stream>>>(rec1, ed1, rowptr, deg, col, h2);
    k_gemm2<<<N_NODES / 16, 256, 0, stream>>>(h2, W2, a2s, a2d, rec2, ed2);
    k_agg2<<<(N_NODES * 8 + 255) / 256, 256, 0, stream>>>(rec2, ed2, rowptr, deg, col, out);
}